// Round 3
// baseline (480.262 us; speedup 1.0000x reference)
//
#include <hip/hip_runtime.h>
#include <hip/hip_bf16.h>
#include <math.h>

#define HIDDEN   4096
#define NEXP     64
#define NTOK     16384
#define KCHUNKS  8
#define KC       (HIDDEN / KCHUNKS)   // 512 k per chunk
#define BK       32                   // k per LDS stage
#define BT       128                  // tokens per block tile
#define XS       132                  // Xs row stride (words): 528B, 16B-aligned
#define WS       68                   // Ws row stride: 272B, 16B-aligned

// inline fn, not a macro: a macro param named `w` collides with float4 member `.w`
__device__ __forceinline__ void fma4(float4& a, float s, const float4& v) {
    a.x = fmaf(s, v.x, a.x);
    a.y = fmaf(s, v.y, a.y);
    a.z = fmaf(s, v.z, a.z);
    a.w = fmaf(s, v.w, a.w);
}

// ---------------- Kernel 1: split-K fp32 GEMM -> partial logits ----------------
// 256 threads (4 waves), tile 128 tok x 64 exp, BK=32, per-thread 8 tok x 4 exp.
// Register-prefetch double buffering: global loads for kb+1 issue before compute of kb.
__global__ __launch_bounds__(256, 4)
void gemm_partial(const float* __restrict__ x, const float* __restrict__ W,
                  float* __restrict__ part) {
    __shared__ float Xs[BK][XS];
    __shared__ float Ws[BK][WS];

    const int tid = threadIdx.x;
    const int t0  = blockIdx.x * BT;
    const int kc  = blockIdx.y;

    // staging mapping: lrow = k-subgroup (float4 along k), lcol = row
    const int lrow = tid & 7;          // 0..7 -> k offset lrow*4
    const int lcol = tid >> 3;         // 0..31
    // compute mapping: i = token group (8 tokens), j = expert group (4 experts)
    const int i = tid & 15;            // 0..15 -> tokens i*8..i*8+7
    const int j = tid >> 4;            // 0..15 -> experts j*4..j*4+3

    float4 acc4[8];
#pragma unroll
    for (int m = 0; m < 8; ++m) acc4[m] = make_float4(0.f, 0.f, 0.f, 0.f);

    const int kbase = kc * KC;

    // prefetch kb=0
    float4 xp0, xp1, xp2, xp3, wp0, wp1;
    {
        const int kg = kbase + lrow * 4;
        xp0 = *(const float4*)&x[(size_t)(t0 +  0 + lcol) * HIDDEN + kg];
        xp1 = *(const float4*)&x[(size_t)(t0 + 32 + lcol) * HIDDEN + kg];
        xp2 = *(const float4*)&x[(size_t)(t0 + 64 + lcol) * HIDDEN + kg];
        xp3 = *(const float4*)&x[(size_t)(t0 + 96 + lcol) * HIDDEN + kg];
        wp0 = *(const float4*)&W[(size_t)( 0 + lcol) * HIDDEN + kg];
        wp1 = *(const float4*)&W[(size_t)(32 + lcol) * HIDDEN + kg];
    }

    for (int kb = 0; kb < KC / BK; ++kb) {
        // write prefetched tile into LDS, transposed [k][row]
        const int kr = lrow * 4;
        Xs[kr + 0][ 0 + lcol] = xp0.x; Xs[kr + 1][ 0 + lcol] = xp0.y;
        Xs[kr + 2][ 0 + lcol] = xp0.z; Xs[kr + 3][ 0 + lcol] = xp0.w;
        Xs[kr + 0][32 + lcol] = xp1.x; Xs[kr + 1][32 + lcol] = xp1.y;
        Xs[kr + 2][32 + lcol] = xp1.z; Xs[kr + 3][32 + lcol] = xp1.w;
        Xs[kr + 0][64 + lcol] = xp2.x; Xs[kr + 1][64 + lcol] = xp2.y;
        Xs[kr + 2][64 + lcol] = xp2.z; Xs[kr + 3][64 + lcol] = xp2.w;
        Xs[kr + 0][96 + lcol] = xp3.x; Xs[kr + 1][96 + lcol] = xp3.y;
        Xs[kr + 2][96 + lcol] = xp3.z; Xs[kr + 3][96 + lcol] = xp3.w;
        Ws[kr + 0][ 0 + lcol] = wp0.x; Ws[kr + 1][ 0 + lcol] = wp0.y;
        Ws[kr + 2][ 0 + lcol] = wp0.z; Ws[kr + 3][ 0 + lcol] = wp0.w;
        Ws[kr + 0][32 + lcol] = wp1.x; Ws[kr + 1][32 + lcol] = wp1.y;
        Ws[kr + 2][32 + lcol] = wp1.z; Ws[kr + 3][32 + lcol] = wp1.w;
        __syncthreads();

        // issue next tile's global loads now -> overlap with compute below
        if (kb + 1 < KC / BK) {
            const int kg = kbase + (kb + 1) * BK + lrow * 4;
            xp0 = *(const float4*)&x[(size_t)(t0 +  0 + lcol) * HIDDEN + kg];
            xp1 = *(const float4*)&x[(size_t)(t0 + 32 + lcol) * HIDDEN + kg];
            xp2 = *(const float4*)&x[(size_t)(t0 + 64 + lcol) * HIDDEN + kg];
            xp3 = *(const float4*)&x[(size_t)(t0 + 96 + lcol) * HIDDEN + kg];
            wp0 = *(const float4*)&W[(size_t)( 0 + lcol) * HIDDEN + kg];
            wp1 = *(const float4*)&W[(size_t)(32 + lcol) * HIDDEN + kg];
        }

#pragma unroll
        for (int kk = 0; kk < BK; ++kk) {
            const float4 xa = *(const float4*)&Xs[kk][i * 8];
            const float4 xb = *(const float4*)&Xs[kk][i * 8 + 4];
            const float4 wv = *(const float4*)&Ws[kk][j * 4];
            fma4(acc4[0], xa.x, wv); fma4(acc4[1], xa.y, wv);
            fma4(acc4[2], xa.z, wv); fma4(acc4[3], xa.w, wv);
            fma4(acc4[4], xb.x, wv); fma4(acc4[5], xb.y, wv);
            fma4(acc4[6], xb.z, wv); fma4(acc4[7], xb.w, wv);
        }
        __syncthreads();
    }

    // write partial logits: part[kc][token][expert], each thread 8 float4 stores
    float* dst = part + ((size_t)kc * NTOK + t0 + i * 8) * NEXP + j * 4;
#pragma unroll
    for (int m = 0; m < 8; ++m)
        *(float4*)&dst[(size_t)m * NEXP] = acc4[m];
}

// ---------------- Kernel 2: reduce partials + bias, softmax, top-2 ----------------
// One wave per token; lane = expert. Butterfly reductions, tie-break lower index.
__global__ __launch_bounds__(256)
void softmax_top2(const float* __restrict__ part, const float* __restrict__ bias,
                  float* __restrict__ out) {
    const int lane = threadIdx.x & 63;
    const int wid  = threadIdx.x >> 6;
    const int t    = blockIdx.x * 4 + wid;

    float l = bias[lane];
#pragma unroll
    for (int c = 0; c < KCHUNKS; ++c)
        l += part[((size_t)c * NTOK + t) * NEXP + lane];

    // wave max
    float m = l;
#pragma unroll
    for (int s = 32; s > 0; s >>= 1)
        m = fmaxf(m, __shfl_xor(m, s, 64));

    // softmax denominator (deterministic butterfly)
    float ssum = expf(l - m);
#pragma unroll
    for (int s = 32; s > 0; s >>= 1)
        ssum += __shfl_xor(ssum, s, 64);

    // top-1: max value, lower index wins ties
    float v1 = l; int i1 = lane;
#pragma unroll
    for (int s = 32; s > 0; s >>= 1) {
        float ov = __shfl_xor(v1, s, 64);
        int   oi = __shfl_xor(i1, s, 64);
        if (ov > v1 || (ov == v1 && oi < i1)) { v1 = ov; i1 = oi; }
    }
    // top-2: exclude i1
    float v2 = (lane == i1) ? -INFINITY : l;
    int   i2 = lane;
#pragma unroll
    for (int s = 32; s > 0; s >>= 1) {
        float ov = __shfl_xor(v2, s, 64);
        int   oi = __shfl_xor(i2, s, 64);
        if (ov > v2 || (ov == v2 && oi < i2)) { v2 = ov; i2 = oi; }
    }

    if (lane == 0) {
        const float inv = 1.0f / ssum;
        out[(size_t)t * 2 + 0] = inv;                    // exp(v1-m)=1 since v1==m
        out[(size_t)t * 2 + 1] = expf(v2 - m) * inv;
        out[(size_t)2 * NTOK + t * 2 + 0] = (float)i1;   // indices read back as float32
        out[(size_t)2 * NTOK + t * 2 + 1] = (float)i2;
    }
}

extern "C" void kernel_launch(void* const* d_in, const int* in_sizes, int n_in,
                              void* d_out, int out_size, void* d_ws, size_t ws_size,
                              hipStream_t stream) {
    const float* x  = (const float*)d_in[0];
    const float* W  = (const float*)d_in[1];
    const float* b  = (const float*)d_in[2];
    float* out  = (float*)d_out;
    float* part = (float*)d_ws;   // KCHUNKS*NTOK*NEXP*4 = 32 MB scratch

    dim3 g1(NTOK / BT, KCHUNKS);  // 128 x 8 = 1024 blocks, 4 waves each
    gemm_partial<<<g1, 256, 0, stream>>>(x, W, part);
    softmax_top2<<<NTOK / 4, 256, 0, stream>>>(part, b, out);
}

// Round 4
// 460.395 us; speedup vs baseline: 1.0432x; 1.0432x over previous
//
#include <hip/hip_runtime.h>
#include <hip/hip_bf16.h>
#include <math.h>

#define HIDDEN   4096
#define NEXP     64
#define NTOK     16384
#define KCHUNKS  8
#define KC       (HIDDEN / KCHUNKS)   // 512 k per chunk
#define BK       32                   // k per LDS stage
#define BT       256                  // tokens per block tile

// inline fn, not a macro (macro param named `w` collides with float4 member .w)
__device__ __forceinline__ void fma4(float4& a, float s, const float4& v) {
    a.x = fmaf(s, v.x, a.x);
    a.y = fmaf(s, v.y, a.y);
    a.z = fmaf(s, v.z, a.z);
    a.w = fmaf(s, v.w, a.w);
}

// ---------------- Kernel 1: split-K fp32 GEMM -> partial logits ----------------
// 256 threads, tile 256 tok x 64 exp, BK=32, per-thread 8 tok x 8 exp (1.0 B/FMA).
// LDS layout XOR-swizzled, unpadded:
//   Xs word = kk*256 + (((t>>2) ^ (kk>>2)) << 2) + (t&3)
//   Ws word = kk*64  + (((e>>2) ^ (kk>>2)) << 2) + (e&3)
// -> staging b32 writes hit 32 distinct banks per phase; b128 fragment reads are
//    per-phase permutations of contiguous chunks. Both conflict-free.
__global__ __launch_bounds__(256, 2)
void gemm_partial(const float* __restrict__ x, const float* __restrict__ W,
                  float* __restrict__ part) {
    __shared__ float Xs[BK * BT];     // 32 KB
    __shared__ float Ws[BK * NEXP];   //  8 KB

    const int tid  = threadIdx.x;
    const int t0   = blockIdx.x * BT;
    const int kc   = blockIdx.y;
    const int lrow = tid & 7;          // k-quad for staging
    const int lcol = tid >> 3;         // 0..31
    const int i    = tid & 31;         // token group: tokens i*4..+3 and +128
    const int j    = tid >> 5;         // expert group 0..7: experts j*4..+3 and +32

    float4 acc[16];                    // [0..7]=lower tokens, [8..15]=upper; [m*2+eh]
#pragma unroll
    for (int m = 0; m < 16; ++m) acc[m] = make_float4(0.f, 0.f, 0.f, 0.f);

    for (int kb = 0; kb < KC / BK; ++kb) {
        const int kg = kc * KC + kb * BK + lrow * 4;

        // stage W tile: 64 exp x 32 k, 2 float4 loads per thread
#pragma unroll
        for (int p = 0; p < 2; ++p) {
            const int e  = lcol + p * 32;
            const float4 wv = *(const float4*)&W[(size_t)e * HIDDEN + kg];
            const int cw = ((((e >> 2) ^ lrow) << 2) + (e & 3));
            Ws[(lrow * 4 + 0) * NEXP + cw] = wv.x;
            Ws[(lrow * 4 + 1) * NEXP + cw] = wv.y;
            Ws[(lrow * 4 + 2) * NEXP + cw] = wv.z;
            Ws[(lrow * 4 + 3) * NEXP + cw] = wv.w;
        }
        // stage X tile: 256 tok x 32 k, 8 float4 loads per thread
#pragma unroll
        for (int s = 0; s < 8; ++s) {
            const int t  = s * 32 + lcol;
            const float4 xv = *(const float4*)&x[(size_t)(t0 + t) * HIDDEN + kg];
            const int cx = ((((t >> 2) ^ lrow) << 2) + (t & 3));
            Xs[(lrow * 4 + 0) * BT + cx] = xv.x;
            Xs[(lrow * 4 + 1) * BT + cx] = xv.y;
            Xs[(lrow * 4 + 2) * BT + cx] = xv.z;
            Xs[(lrow * 4 + 3) * BT + cx] = xv.w;
        }
        __syncthreads();

#pragma unroll
        for (int g = 0; g < 8; ++g) {
            const int xo = ((i ^ g) << 2);   // swizzled chunk for this kk-quad
            const int wo = ((j ^ g) << 2);
#pragma unroll
            for (int q = 0; q < 4; ++q) {
                const int kk = (g << 2) + q;
                const float4 xa = *(const float4*)&Xs[kk * BT + xo];
                const float4 xb = *(const float4*)&Xs[kk * BT + xo + 128];
                const float4 wa = *(const float4*)&Ws[kk * NEXP + wo];
                const float4 wb = *(const float4*)&Ws[kk * NEXP + wo + 32];
                fma4(acc[0],  xa.x, wa); fma4(acc[1],  xa.x, wb);
                fma4(acc[2],  xa.y, wa); fma4(acc[3],  xa.y, wb);
                fma4(acc[4],  xa.z, wa); fma4(acc[5],  xa.z, wb);
                fma4(acc[6],  xa.w, wa); fma4(acc[7],  xa.w, wb);
                fma4(acc[8],  xb.x, wa); fma4(acc[9],  xb.x, wb);
                fma4(acc[10], xb.y, wa); fma4(acc[11], xb.y, wb);
                fma4(acc[12], xb.z, wa); fma4(acc[13], xb.z, wb);
                fma4(acc[14], xb.w, wa); fma4(acc[15], xb.w, wb);
            }
        }
        __syncthreads();
    }

    // write partial logits: part[kc][token][expert]
    const size_t obase = ((size_t)kc * NTOK + t0) * NEXP;
#pragma unroll
    for (int m = 0; m < 4; ++m) {
        float* r0 = part + obase + (size_t)(i * 4 + m) * NEXP;
        float* r1 = part + obase + (size_t)(i * 4 + m + 128) * NEXP;
        *(float4*)&r0[j * 4]      = acc[m * 2 + 0];
        *(float4*)&r0[j * 4 + 32] = acc[m * 2 + 1];
        *(float4*)&r1[j * 4]      = acc[8 + m * 2 + 0];
        *(float4*)&r1[j * 4 + 32] = acc[8 + m * 2 + 1];
    }
}

// ---------------- Kernel 2: reduce partials + bias, softmax, top-2 ----------------
// One wave per token; lane = expert. Butterfly reductions, tie-break lower index.
__global__ __launch_bounds__(256)
void softmax_top2(const float* __restrict__ part, const float* __restrict__ bias,
                  float* __restrict__ out) {
    const int lane = threadIdx.x & 63;
    const int wid  = threadIdx.x >> 6;
    const int t    = blockIdx.x * 4 + wid;

    float l = bias[lane];
#pragma unroll
    for (int c = 0; c < KCHUNKS; ++c)
        l += part[((size_t)c * NTOK + t) * NEXP + lane];

    // wave max
    float m = l;
#pragma unroll
    for (int s = 32; s > 0; s >>= 1)
        m = fmaxf(m, __shfl_xor(m, s, 64));

    // softmax denominator (deterministic butterfly)
    float ssum = expf(l - m);
#pragma unroll
    for (int s = 32; s > 0; s >>= 1)
        ssum += __shfl_xor(ssum, s, 64);

    // top-1: max value, lower index wins ties
    float v1 = l; int i1 = lane;
#pragma unroll
    for (int s = 32; s > 0; s >>= 1) {
        float ov = __shfl_xor(v1, s, 64);
        int   oi = __shfl_xor(i1, s, 64);
        if (ov > v1 || (ov == v1 && oi < i1)) { v1 = ov; i1 = oi; }
    }
    // top-2: exclude i1
    float v2 = (lane == i1) ? -INFINITY : l;
    int   i2 = lane;
#pragma unroll
    for (int s = 32; s > 0; s >>= 1) {
        float ov = __shfl_xor(v2, s, 64);
        int   oi = __shfl_xor(i2, s, 64);
        if (ov > v2 || (ov == v2 && oi < i2)) { v2 = ov; i2 = oi; }
    }

    if (lane == 0) {
        const float inv = 1.0f / ssum;
        out[(size_t)t * 2 + 0] = inv;                    // exp(v1-m)=1 since v1==m
        out[(size_t)t * 2 + 1] = expf(v2 - m) * inv;
        out[(size_t)2 * NTOK + t * 2 + 0] = (float)i1;   // indices read back as float32
        out[(size_t)2 * NTOK + t * 2 + 1] = (float)i2;
    }
}

extern "C" void kernel_launch(void* const* d_in, const int* in_sizes, int n_in,
                              void* d_out, int out_size, void* d_ws, size_t ws_size,
                              hipStream_t stream) {
    const float* x  = (const float*)d_in[0];
    const float* W  = (const float*)d_in[1];
    const float* b  = (const float*)d_in[2];
    float* out  = (float*)d_out;
    float* part = (float*)d_ws;   // KCHUNKS*NTOK*NEXP*4 = 32 MB scratch

    dim3 g1(NTOK / BT, KCHUNKS);  // 64 x 8 = 512 blocks
    gemm_partial<<<g1, 256, 0, stream>>>(x, W, part);
    softmax_top2<<<NTOK / 4, 256, 0, stream>>>(part, b, out);
}